// Round 8
// baseline (142.978 us; speedup 1.0000x reference)
//
#include <hip/hip_runtime.h>
#include <hip/hip_bf16.h>
#include <math.h>

// Problem constants
#define NB 4
#define NC 4
#define NH 4
#define NN 1024
#define NF 64
#define NCOMBO 64
#define LEAK 0.2f

typedef __attribute__((ext_vector_type(8)))  short  short8;
typedef __attribute__((ext_vector_type(16))) float  float16;

// packed RNE f32x2 -> bf16x2 via v_cvt_pk_bf16_f32
static __device__ __forceinline__ unsigned pk_bf16(float a, float b) {
    union { __hip_bfloat162 h; unsigned u; } cv;
    cv.h = __float22bfloat162_rn(make_float2(a, b));
    return cv.u;
}

// tanh via hardware exp+rcp: 1 - 2/(1+e^{2x}); err ~1e-6, saturates correctly
static __device__ __forceinline__ float fast_tanh(float x) {
    const float e = __expf(2.f * x);
    return 1.f - 2.f * __builtin_amdgcn_rcpf(1.f + e);
}

// ---------------------------------------------------------------------------
// gA: producer. Block idx -> (g, tile) with XCD-aligned swizzle so idx%8
// (XCD round-robin) == g>>3 in BOTH kernels -> per-XCD L2 keeps its 8 g's.
//   phase A: hp = h@w fp32 LDS-tiled GEMM -> hpt (bf16, MFMA-B-frag order),
//            asrc, and factored-exp tables edP=exp(dst), edN=exp(0.2 dst)
//   phase B: adjacency bitmask chunk (ballot)
// ---------------------------------------------------------------------------
__global__ __launch_bounds__(256) void gA_produce(
    const float* __restrict__ h, const float* __restrict__ adj,
    const float* __restrict__ w, const float* __restrict__ a_src,
    const float* __restrict__ a_dst,
    unsigned short* __restrict__ hpt, float* __restrict__ asrc,
    float* __restrict__ edPt, float* __restrict__ edNt,
    unsigned long long* __restrict__ bits)
{
    __shared__ __align__(16) char smem[33536];
    float* hT     = (float*)smem;              // [64*65] stride 65
    float* w_s    = (float*)(smem + 16640);    // [64*64]
    float* as_lds = (float*)(smem + 33024);    // [64]
    float* ad_lds = (float*)(smem + 33280);    // [64]

    const int idx  = blockIdx.x;
    const int t    = threadIdx.x;
    const int g    = (idx & 7)*8 + ((idx >> 3) & 7);   // 0..63
    const int tile = idx >> 6;                          // 0..15
    const int b = g >> 4, c = (g >> 2) & 3, hh = g & 3;
    const int tr = t >> 4, tc = t & 15;

    const float4* wsrc = (const float4*)(w + ((size_t)(c*NH + hh))*NF*NF);
    #pragma unroll
    for (int i = 0; i < 4; ++i)
        ((float4*)w_s)[t + i*256] = wsrc[t + i*256];
    if (t < NF) {
        as_lds[t] = a_src[(c*NH + hh)*NF + t];
        ad_lds[t] = a_dst[(c*NH + hh)*NF + t];
    }
    const float* hsrc = h + (((size_t)(b*NC + c))*NN + tile*64)*NF;
    #pragma unroll
    for (int i = 0; i < 4; ++i) {
        const int r = (t >> 4) + i*16, f4 = (t & 15)*4;
        const float4 v = *(const float4*)&hsrc[r*NF + f4];
        hT[(f4+0)*65 + r] = v.x; hT[(f4+1)*65 + r] = v.y;
        hT[(f4+2)*65 + r] = v.z; hT[(f4+3)*65 + r] = v.w;
    }
    __syncthreads();

    float acc[4][4] = {{0.f}};
    #pragma unroll 8
    for (int f = 0; f < 64; ++f) {
        const float4 hv = *(const float4*)&hT[f*65 + tr*4];
        const float4 wv = *(const float4*)&w_s[f*64 + tc*4];
        acc[0][0] = fmaf(hv.x, wv.x, acc[0][0]);
        acc[0][1] = fmaf(hv.x, wv.y, acc[0][1]);
        acc[0][2] = fmaf(hv.x, wv.z, acc[0][2]);
        acc[0][3] = fmaf(hv.x, wv.w, acc[0][3]);
        acc[1][0] = fmaf(hv.y, wv.x, acc[1][0]);
        acc[1][1] = fmaf(hv.y, wv.y, acc[1][1]);
        acc[1][2] = fmaf(hv.y, wv.z, acc[1][2]);
        acc[1][3] = fmaf(hv.y, wv.w, acc[1][3]);
        acc[2][0] = fmaf(hv.z, wv.x, acc[2][0]);
        acc[2][1] = fmaf(hv.z, wv.y, acc[2][1]);
        acc[2][2] = fmaf(hv.z, wv.z, acc[2][2]);
        acc[2][3] = fmaf(hv.z, wv.w, acc[2][3]);
        acc[3][0] = fmaf(hv.w, wv.x, acc[3][0]);
        acc[3][1] = fmaf(hv.w, wv.y, acc[3][1]);
        acc[3][2] = fmaf(hv.w, wv.z, acc[3][2]);
        acc[3][3] = fmaf(hv.w, wv.w, acc[3][3]);
    }

    float ps[4] = {0.f,0.f,0.f,0.f}, pd[4] = {0.f,0.f,0.f,0.f};
    #pragma unroll
    for (int r = 0; r < 4; ++r)
        #pragma unroll
        for (int cc = 0; cc < 4; ++cc) {
            const float tt = fast_tanh(acc[r][cc]);
            ps[r] = fmaf(tt, as_lds[tc*4+cc], ps[r]);
            pd[r] = fmaf(tt, ad_lds[tc*4+cc], pd[r]);
        }
    __syncthreads();                 // hT dead -> overlay
    float* redS = (float*)smem;      // [64][16]
    float* redD = redS + 1024;
    #pragma unroll
    for (int r = 0; r < 4; ++r) {
        redS[(tr*4+r)*16 + tc] = ps[r];
        redD[(tr*4+r)*16 + tc] = pd[r];
    }
    __syncthreads();
    if (t < 64) {
        float4 s0 = *(const float4*)&redS[t*16],   s1 = *(const float4*)&redS[t*16+4];
        float4 s2 = *(const float4*)&redS[t*16+8], s3 = *(const float4*)&redS[t*16+12];
        asrc[(size_t)g*NN + tile*64 + t] =
            (s0.x+s0.y+s0.z+s0.w) + (s1.x+s1.y+s1.z+s1.w) +
            (s2.x+s2.y+s2.z+s2.w) + (s3.x+s3.y+s3.z+s3.w);
        float4 d0 = *(const float4*)&redD[t*16],   d1 = *(const float4*)&redD[t*16+4];
        float4 d2 = *(const float4*)&redD[t*16+8], d3 = *(const float4*)&redD[t*16+12];
        const float dsum =
            (d0.x+d0.y+d0.z+d0.w) + (d1.x+d1.y+d1.z+d1.w) +
            (d2.x+d2.y+d2.z+d2.w) + (d3.x+d3.y+d3.z+d3.w);
        edPt[(size_t)g*NN + tile*64 + t] = __expf(dsum);
        edNt[(size_t)g*NN + tile*64 + t] = __expf(LEAK*dsum);
    }
    // fragment-order bf16 hp write: j = tr*4 + r, o = tc*4 + cc
    #pragma unroll
    for (int cc = 0; cc < 4; ++cc) {
        const int o = tc*4 + cc;
        const int pos = (((((tr>>2)*2 + (o>>5))*2 + ((tr>>1)&1))*32 + (o&31))*8)
                        + (tr&1)*4;
        uint2 pk;
        pk.x = pk_bf16(acc[0][cc], acc[1][cc]);
        pk.y = pk_bf16(acc[2][cc], acc[3][cc]);
        *(uint2*)&hpt[((size_t)g*16 + tile)*4096 + pos] = pk;
    }

    // ---- phase B: adjacency bitmask (this block's 4096-element chunk) ----
    {
        const int base = idx*4096;       // 1024 blocks x 4096 = 4M elements
        #pragma unroll
        for (int q = 0; q < 16; ++q) {
            const int e  = base + q*256 + t;
            const int j  = e & (NN-1);
            const int i  = (e >> 10) & (NN-1);
            const int bb = e >> 20;
            const bool pred = (adj[e] != 0.f) || (j == i);
            const unsigned long long m = __ballot(pred);
            if ((t & 63) == 0) bits[((size_t)bb*NN + i)*16 + (j >> 6)] = m;
        }
    }
}

// ---------------------------------------------------------------------------
// gC: consumer. Block idx -> (g, it), same swizzle. 64 i-rows per block,
// 4 waves: wave = (rg = w>>1 row group, jh = w&1 K-half). Barrier-free PV
// loop: B-fragments + exp tables stream from global (L2-resident, ~1MB/XCD),
// mask bits from LDS. Per-row softmax scale cancels in normalization:
//   p_raw = mask * max(edP[j], ratio_i*edN[j]),  ratio_i = exp((LEAK-1)*sv_i)
// = exp(lrelu(sv_i + dst_j)) / exp(sv_i)  — exact softmax after row-divide.
// ---------------------------------------------------------------------------
__global__ __launch_bounds__(256, 4) void gC_attn(
    const unsigned short* __restrict__ hpt, const float* __restrict__ asrc,
    const float* __restrict__ edPt, const float* __restrict__ edNt,
    const unsigned long long* __restrict__ bits, float* __restrict__ out)
{
    __shared__ __align__(16) char smem[26368];
    unsigned long long* bits_lds = (unsigned long long*)smem;  // [64*17] 8704B
    float* comb   = (float*)(smem + 8704);                     // [2*64*34] 17408B
    float* ps_buf = (float*)(smem + 26112);                    // [64]

    const int idx = blockIdx.x;
    const int t   = threadIdx.x;
    const int g   = (idx & 7)*8 + ((idx >> 3) & 7);
    const int it  = idx >> 6;
    const int b   = g >> 4;
    const int i0  = it*64;
    const int wv = t >> 6, lane = t & 63;
    const int l31 = lane & 31, half = lane >> 5;
    const int rg = wv >> 1, jh = wv & 1;
    const int myrow = rg*32 + l31;

    {
        const unsigned long long* bsrc = bits + ((size_t)b*NN + i0)*16;
        #pragma unroll
        for (int q = 0; q < 4; ++q) {
            const int e = q*256 + t;
            bits_lds[(e >> 4)*17 + (e & 15)] = bsrc[e];
        }
    }
    __syncthreads();

    const float sv    = asrc[(size_t)g*NN + i0 + myrow];
    const float ratio = __expf((LEAK - 1.f)*sv);

    float16 acc0, acc1;
    #pragma unroll
    for (int i = 0; i < 16; ++i) { acc0[i] = 0.f; acc1[i] = 0.f; }
    float psum = 0.f;

    const float* tbP = edPt + (size_t)g*NN;
    const float* tbN = edNt + (size_t)g*NN;
    const unsigned short* hq0 = hpt + (size_t)g*16*4096;

    #pragma unroll 2
    for (int jt = 0; jt < 16; ++jt) {
        const unsigned long long wb = bits_lds[myrow*17 + jt];
        const float* tP = tbP + jt*64;
        const float* tN = tbN + jt*64;
        const unsigned short* hq = hq0 + jt*4096;

        #pragma unroll
        for (int kk = 0; kk < 2; ++kk) {
            const int ks = jh*2 + kk;
            const int jo = ks*16 + half*8;
            const float4 P0 = *(const float4*)&tP[jo];
            const float4 P1 = *(const float4*)&tP[jo + 4];
            const float4 N0 = *(const float4*)&tN[jo];
            const float4 N1 = *(const float4*)&tN[jo + 4];
            const short8 b0 = *(const short8*)&hq[(((ks*2 + 0)*2 + half)*32 + l31)*8];
            const short8 b1 = *(const short8*)&hq[(((ks*2 + 1)*2 + half)*32 + l31)*8];
            const unsigned bb = (unsigned)(wb >> jo) & 0xffu;

            float p0, p1, p2, p3, p4, p5, p6, p7;
            p0 = fmaxf(P0.x, ratio*N0.x); p0 = (bb & 1u)   ? p0 : 0.f;
            p1 = fmaxf(P0.y, ratio*N0.y); p1 = (bb & 2u)   ? p1 : 0.f;
            p2 = fmaxf(P0.z, ratio*N0.z); p2 = (bb & 4u)   ? p2 : 0.f;
            p3 = fmaxf(P0.w, ratio*N0.w); p3 = (bb & 8u)   ? p3 : 0.f;
            p4 = fmaxf(P1.x, ratio*N1.x); p4 = (bb & 16u)  ? p4 : 0.f;
            p5 = fmaxf(P1.y, ratio*N1.y); p5 = (bb & 32u)  ? p5 : 0.f;
            p6 = fmaxf(P1.z, ratio*N1.z); p6 = (bb & 64u)  ? p6 : 0.f;
            p7 = fmaxf(P1.w, ratio*N1.w); p7 = (bb & 128u) ? p7 : 0.f;
            psum += ((p0 + p1) + (p2 + p3)) + ((p4 + p5) + (p6 + p7));

            union { short8 v; unsigned u[4]; } af;
            af.u[0] = pk_bf16(p0, p1);
            af.u[1] = pk_bf16(p2, p3);
            af.u[2] = pk_bf16(p4, p5);
            af.u[3] = pk_bf16(p6, p7);

            acc0 = __builtin_amdgcn_mfma_f32_32x32x16_bf16(af.v, b0, acc0, 0, 0, 0);
            acc1 = __builtin_amdgcn_mfma_f32_32x32x16_bf16(af.v, b1, acc1, 0, 0, 0);
        }
    }

    // combine wave-pair partials (jh splits K); halves cover j%16 split
    psum += __shfl_xor(psum, 32);
    __syncthreads();

    if (jh == 1) {
        float* cb = comb + (rg*64 + lane)*34;
        #pragma unroll
        for (int i = 0; i < 8; ++i) {
            float2 v0; v0.x = acc0[2*i]; v0.y = acc0[2*i+1];
            float2 v1; v1.x = acc1[2*i]; v1.y = acc1[2*i+1];
            *(float2*)&cb[2*i]      = v0;
            *(float2*)&cb[16 + 2*i] = v1;
        }
        if (lane < 32) ps_buf[rg*32 + l31] = psum;
    }
    __syncthreads();
    if (jh == 0) {
        const float* cb = comb + (rg*64 + lane)*34;
        #pragma unroll
        for (int i = 0; i < 8; ++i) {
            const float2 v0 = *(const float2*)&cb[2*i];
            const float2 v1 = *(const float2*)&cb[16 + 2*i];
            acc0[2*i] += v0.x; acc0[2*i+1] += v0.y;
            acc1[2*i] += v1.x; acc1[2*i+1] += v1.y;
        }
        psum += ps_buf[rg*32 + l31];
        if (lane < 32) ps_buf[rg*32 + l31] = psum;
    }
    __syncthreads();
    if (jh == 0) {
        #pragma unroll
        for (int reg = 0; reg < 16; ++reg) {
            const int r = (reg & 3) + 8*(reg >> 2) + 4*half;
            const float inv = __builtin_amdgcn_rcpf(ps_buf[rg*32 + r]);
            const size_t base = ((size_t)g*NN + i0 + rg*32 + r)*NF;
            out[base + l31]      = acc0[reg] * inv;
            out[base + l31 + 32] = acc1[reg] * inv;
        }
    }
}

// ---------------------------------------------------------------------------
extern "C" void kernel_launch(void* const* d_in, const int* in_sizes, int n_in,
                              void* d_out, int out_size, void* d_ws, size_t ws_size,
                              hipStream_t stream)
{
    const float* h     = (const float*)d_in[0];
    const float* adj   = (const float*)d_in[1];
    const float* w     = (const float*)d_in[2];
    const float* a_src = (const float*)d_in[3];
    const float* a_dst = (const float*)d_in[4];
    float* out = (float*)d_out;

    char* ws = (char*)d_ws;
    // ws: hpt bf16 [64][16][4096] frag-order (8,388,608) | asrc (262,144)
    //     | edP (262,144) | edN (262,144) | bits u64 [4][1024][16] (524,288)
    unsigned short* hpt = (unsigned short*)ws;
    float* asrc         = (float*)(ws + 8388608);
    float* edP          = (float*)(ws + 8388608 + 262144);
    float* edN          = (float*)(ws + 8388608 + 524288);
    unsigned long long* bits = (unsigned long long*)(ws + 8388608 + 786432);

    gA_produce<<<dim3(1024), dim3(256), 0, stream>>>(
        h, adj, w, a_src, a_dst, hpt, asrc, edP, edN, bits);
    gC_attn<<<dim3(1024), dim3(256), 0, stream>>>(
        hpt, asrc, edP, edN, bits, out);
}

// Round 9
// 133.456 us; speedup vs baseline: 1.0714x; 1.0714x over previous
//
#include <hip/hip_runtime.h>
#include <hip/hip_bf16.h>
#include <math.h>

// Problem constants
#define NB 4
#define NC 4
#define NH 4
#define NN 1024
#define NF 64
#define NCOMBO 64
#define LEAK 0.2f

typedef __attribute__((ext_vector_type(8)))  short  short8;
typedef __attribute__((ext_vector_type(16))) float  float16;

// packed RNE f32x2 -> bf16x2 via v_cvt_pk_bf16_f32 (.x -> low 16, .y -> high 16)
static __device__ __forceinline__ unsigned pk_bf16(float a, float b) {
    union { __hip_bfloat162 h; unsigned u; } cv;
    cv.h = __float22bfloat162_rn(make_float2(a, b));
    return cv.u;
}

// tanh via hardware exp+rcp: 1 - 2/(1+e^{2x}); err ~1e-6, saturates correctly
static __device__ __forceinline__ float fast_tanh(float x) {
    const float e = __expf(2.f * x);
    return 1.f - 2.f * __builtin_amdgcn_rcpf(1.f + e);
}

// async global->LDS, 16B per lane (dst = wave-uniform base + lane*16)
static __device__ __forceinline__ void async_cp16(const void* gsrc, void* ldst) {
    __builtin_amdgcn_global_load_lds(
        (const __attribute__((address_space(1))) unsigned int*)gsrc,
        (__attribute__((address_space(3))) unsigned int*)ldst, 16, 0, 0);
}

// ---------------------------------------------------------------------------
// gA: producer (UNCHANGED from R7 for attribution). Block idx -> (g, tile),
// XCD-aligned swizzle (idx%8 == g>>3 in both kernels).
//   phase A: hp = h@w fp32 LDS-tiled GEMM -> hpt (bf16, MFMA-B-frag order),
//            asrc, and factored-exp tables edP=exp(dst), edN=exp(0.2 dst)
//   phase B: adjacency bitmask chunk (ballot)
// ---------------------------------------------------------------------------
__global__ __launch_bounds__(256) void gA_produce(
    const float* __restrict__ h, const float* __restrict__ adj,
    const float* __restrict__ w, const float* __restrict__ a_src,
    const float* __restrict__ a_dst,
    unsigned short* __restrict__ hpt, float* __restrict__ asrc,
    float* __restrict__ edPt, float* __restrict__ edNt,
    unsigned long long* __restrict__ bits)
{
    __shared__ __align__(16) char smem[33536];
    float* hT     = (float*)smem;              // [64*65] stride 65
    float* w_s    = (float*)(smem + 16640);    // [64*64]
    float* as_lds = (float*)(smem + 33024);    // [64]
    float* ad_lds = (float*)(smem + 33280);    // [64]

    const int idx  = blockIdx.x;
    const int t    = threadIdx.x;
    const int g    = (idx & 7)*8 + ((idx >> 3) & 7);   // 0..63
    const int tile = idx >> 6;                          // 0..15
    const int b = g >> 4, c = (g >> 2) & 3, hh = g & 3;
    const int tr = t >> 4, tc = t & 15;

    const float4* wsrc = (const float4*)(w + ((size_t)(c*NH + hh))*NF*NF);
    #pragma unroll
    for (int i = 0; i < 4; ++i)
        ((float4*)w_s)[t + i*256] = wsrc[t + i*256];
    if (t < NF) {
        as_lds[t] = a_src[(c*NH + hh)*NF + t];
        ad_lds[t] = a_dst[(c*NH + hh)*NF + t];
    }
    const float* hsrc = h + (((size_t)(b*NC + c))*NN + tile*64)*NF;
    #pragma unroll
    for (int i = 0; i < 4; ++i) {
        const int r = (t >> 4) + i*16, f4 = (t & 15)*4;
        const float4 v = *(const float4*)&hsrc[r*NF + f4];
        hT[(f4+0)*65 + r] = v.x; hT[(f4+1)*65 + r] = v.y;
        hT[(f4+2)*65 + r] = v.z; hT[(f4+3)*65 + r] = v.w;
    }
    __syncthreads();

    float acc[4][4] = {{0.f}};
    #pragma unroll 8
    for (int f = 0; f < 64; ++f) {
        const float4 hv = *(const float4*)&hT[f*65 + tr*4];
        const float4 wv = *(const float4*)&w_s[f*64 + tc*4];
        acc[0][0] = fmaf(hv.x, wv.x, acc[0][0]);
        acc[0][1] = fmaf(hv.x, wv.y, acc[0][1]);
        acc[0][2] = fmaf(hv.x, wv.z, acc[0][2]);
        acc[0][3] = fmaf(hv.x, wv.w, acc[0][3]);
        acc[1][0] = fmaf(hv.y, wv.x, acc[1][0]);
        acc[1][1] = fmaf(hv.y, wv.y, acc[1][1]);
        acc[1][2] = fmaf(hv.y, wv.z, acc[1][2]);
        acc[1][3] = fmaf(hv.y, wv.w, acc[1][3]);
        acc[2][0] = fmaf(hv.z, wv.x, acc[2][0]);
        acc[2][1] = fmaf(hv.z, wv.y, acc[2][1]);
        acc[2][2] = fmaf(hv.z, wv.z, acc[2][2]);
        acc[2][3] = fmaf(hv.z, wv.w, acc[2][3]);
        acc[3][0] = fmaf(hv.w, wv.x, acc[3][0]);
        acc[3][1] = fmaf(hv.w, wv.y, acc[3][1]);
        acc[3][2] = fmaf(hv.w, wv.z, acc[3][2]);
        acc[3][3] = fmaf(hv.w, wv.w, acc[3][3]);
    }

    float ps[4] = {0.f,0.f,0.f,0.f}, pd[4] = {0.f,0.f,0.f,0.f};
    #pragma unroll
    for (int r = 0; r < 4; ++r)
        #pragma unroll
        for (int cc = 0; cc < 4; ++cc) {
            const float tt = fast_tanh(acc[r][cc]);
            ps[r] = fmaf(tt, as_lds[tc*4+cc], ps[r]);
            pd[r] = fmaf(tt, ad_lds[tc*4+cc], pd[r]);
        }
    __syncthreads();                 // hT dead -> overlay
    float* redS = (float*)smem;      // [64][16]
    float* redD = redS + 1024;
    #pragma unroll
    for (int r = 0; r < 4; ++r) {
        redS[(tr*4+r)*16 + tc] = ps[r];
        redD[(tr*4+r)*16 + tc] = pd[r];
    }
    __syncthreads();
    if (t < 64) {
        float4 s0 = *(const float4*)&redS[t*16],   s1 = *(const float4*)&redS[t*16+4];
        float4 s2 = *(const float4*)&redS[t*16+8], s3 = *(const float4*)&redS[t*16+12];
        asrc[(size_t)g*NN + tile*64 + t] =
            (s0.x+s0.y+s0.z+s0.w) + (s1.x+s1.y+s1.z+s1.w) +
            (s2.x+s2.y+s2.z+s2.w) + (s3.x+s3.y+s3.z+s3.w);
        float4 d0 = *(const float4*)&redD[t*16],   d1 = *(const float4*)&redD[t*16+4];
        float4 d2 = *(const float4*)&redD[t*16+8], d3 = *(const float4*)&redD[t*16+12];
        const float dsum =
            (d0.x+d0.y+d0.z+d0.w) + (d1.x+d1.y+d1.z+d1.w) +
            (d2.x+d2.y+d2.z+d2.w) + (d3.x+d3.y+d3.z+d3.w);
        edPt[(size_t)g*NN + tile*64 + t] = __expf(dsum);
        edNt[(size_t)g*NN + tile*64 + t] = __expf(LEAK*dsum);
    }
    // fragment-order bf16 hp write: j = tr*4 + r, o = tc*4 + cc
    #pragma unroll
    for (int cc = 0; cc < 4; ++cc) {
        const int o = tc*4 + cc;
        const int pos = (((((tr>>2)*2 + (o>>5))*2 + ((tr>>1)&1))*32 + (o&31))*8)
                        + (tr&1)*4;
        uint2 pk;
        pk.x = pk_bf16(acc[0][cc], acc[1][cc]);
        pk.y = pk_bf16(acc[2][cc], acc[3][cc]);
        *(uint2*)&hpt[((size_t)g*16 + tile)*4096 + pos] = pk;
    }

    // ---- phase B: adjacency bitmask (this block's 4096-element chunk) ----
    {
        const int base = idx*4096;       // 1024 blocks x 4096 = 4M elements
        #pragma unroll
        for (int q = 0; q < 16; ++q) {
            const int e  = base + q*256 + t;
            const int j  = e & (NN-1);
            const int i  = (e >> 10) & (NN-1);
            const int bb = e >> 20;
            const bool pred = (adj[e] != 0.f) || (j == i);
            const unsigned long long m = __ballot(pred);
            if ((t & 63) == 0) bits[((size_t)bb*NN + i)*16 + (j >> 6)] = m;
        }
    }
}

// ---------------------------------------------------------------------------
// gC: consumer. R5-proven double-buffered async-DMA staging of frag tiles +
// two new pipe cuts:
//   - tables packed (edN,edP) bf16-pair per j in LDS: 2 b128/kk (was 4)
//   - row-sum via ones-MFMA into acc2 (same bf16 p as numerator): no psum
//     VALU adds, no shfl reduction; rcp applied directly per output reg.
// P-gen ratio form: p = mask * max(edP_j, ratio_i*edN_j),
// ratio_i = exp((LEAK-1)*sv_i)  — softmax exact up to a row constant.
// ---------------------------------------------------------------------------
__global__ __launch_bounds__(256, 4) void gC_attn(
    const unsigned short* __restrict__ hpt, const float* __restrict__ asrc,
    const float* __restrict__ edPt, const float* __restrict__ edNt,
    const unsigned long long* __restrict__ bits, float* __restrict__ out)
{
    // [0,16384) frag dbuf | [16384,20480) packed tbl | overlay comb on [0,20480)
    // [20480,29184) bits_lds (64*17 u64) | [29184,29696) psum2 [2][64]
    __shared__ __align__(16) char smem[29696];
    unsigned short* fragB = (unsigned short*)smem;
    unsigned*       tbl   = (unsigned*)(smem + 16384);
    float*          comb  = (float*)smem;
    unsigned long long* bits_lds = (unsigned long long*)(smem + 20480);
    float*          psum2 = (float*)(smem + 29184);

    const int idx = blockIdx.x;
    const int t   = threadIdx.x;
    const int g   = (idx & 7)*8 + ((idx >> 3) & 7);
    const int it  = idx >> 6;
    const int b   = g >> 4;
    const int i0  = it*64;
    const int wv = t >> 6, lane = t & 63;
    const int l31 = lane & 31, half = lane >> 5;
    const int rg = wv >> 1, jh = wv & 1;
    const int myrow = rg*32 + l31;

    // DMA tile 0 into buffer 0 (verbatim copy; hpt is pre-swizzled frag order)
    {
        const char* gs = (const char*)hpt + ((size_t)g*16)*8192 + wv*2048 + lane*16;
        char* ls = smem + wv*2048;
        async_cp16(gs, ls);
        async_cp16(gs + 1024, ls + 1024);
    }
    // pack tables: tbl[j] = (bf16(edN) low | bf16(edP) high)
    #pragma unroll
    for (int q = 0; q < 4; ++q) {
        const int j = q*256 + t;
        tbl[j] = pk_bf16(edNt[(size_t)g*NN + j], edPt[(size_t)g*NN + j]);
    }
    // mask bits
    {
        const unsigned long long* bsrc = bits + ((size_t)b*NN + i0)*16;
        #pragma unroll
        for (int q = 0; q < 4; ++q) {
            const int e = q*256 + t;
            bits_lds[(e >> 4)*17 + (e & 15)] = bsrc[e];
        }
    }
    const float sv    = asrc[(size_t)g*NN + i0 + myrow];
    const float ratio = __expf((LEAK - 1.f)*sv);

    // bf16 1.0 B-fragment for the row-sum MFMA
    union { short8 v; unsigned short u[8]; } ONES;
    #pragma unroll
    for (int i = 0; i < 8; ++i) ONES.u[i] = 0x3F80;

    float16 acc0, acc1, acc2;
    #pragma unroll
    for (int i = 0; i < 16; ++i) { acc0[i] = 0.f; acc1[i] = 0.f; acc2[i] = 0.f; }

    for (int jt = 0; jt < 16; ++jt) {
        __syncthreads();   // tile jt's DMA landed; other-buffer reads done
        const int fb = jt & 1;
        if (jt < 15) {
            const char* gs = (const char*)hpt + ((size_t)g*16 + jt + 1)*8192
                             + wv*2048 + lane*16;
            char* ls = smem + ((jt + 1) & 1)*8192 + wv*2048;
            async_cp16(gs, ls);
            async_cp16(gs + 1024, ls + 1024);
        }
        const unsigned long long wb = bits_lds[myrow*17 + jt];

        #pragma unroll
        for (int kk = 0; kk < 2; ++kk) {
            const int ks = jh*2 + kk;
            const int jo = ks*16 + half*8;
            const uint4 Ta = *(const uint4*)&tbl[jt*64 + jo];
            const uint4 Tb = *(const uint4*)&tbl[jt*64 + jo + 4];
            const short8 b0 = *(const short8*)
                &fragB[fb*4096 + (((ks*2 + 0)*2 + half)*32 + l31)*8];
            const short8 b1 = *(const short8*)
                &fragB[fb*4096 + (((ks*2 + 1)*2 + half)*32 + l31)*8];
            const unsigned bb = (unsigned)(wb >> jo) & 0xffu;

            float p0, p1, p2, p3, p4, p5, p6, p7;
            {
                union { unsigned u; float f; } hi, lo;
                hi.u = Ta.x & 0xffff0000u; lo.u = Ta.x << 16;
                p0 = fmaxf(hi.f, ratio*lo.f); p0 = (bb & 1u)   ? p0 : 0.f;
                hi.u = Ta.y & 0xffff0000u; lo.u = Ta.y << 16;
                p1 = fmaxf(hi.f, ratio*lo.f); p1 = (bb & 2u)   ? p1 : 0.f;
                hi.u = Ta.z & 0xffff0000u; lo.u = Ta.z << 16;
                p2 = fmaxf(hi.f, ratio*lo.f); p2 = (bb & 4u)   ? p2 : 0.f;
                hi.u = Ta.w & 0xffff0000u; lo.u = Ta.w << 16;
                p3 = fmaxf(hi.f, ratio*lo.f); p3 = (bb & 8u)   ? p3 : 0.f;
                hi.u = Tb.x & 0xffff0000u; lo.u = Tb.x << 16;
                p4 = fmaxf(hi.f, ratio*lo.f); p4 = (bb & 16u)  ? p4 : 0.f;
                hi.u = Tb.y & 0xffff0000u; lo.u = Tb.y << 16;
                p5 = fmaxf(hi.f, ratio*lo.f); p5 = (bb & 32u)  ? p5 : 0.f;
                hi.u = Tb.z & 0xffff0000u; lo.u = Tb.z << 16;
                p6 = fmaxf(hi.f, ratio*lo.f); p6 = (bb & 64u)  ? p6 : 0.f;
                hi.u = Tb.w & 0xffff0000u; lo.u = Tb.w << 16;
                p7 = fmaxf(hi.f, ratio*lo.f); p7 = (bb & 128u) ? p7 : 0.f;
            }

            union { short8 v; unsigned u[4]; } af;
            af.u[0] = pk_bf16(p0, p1);
            af.u[1] = pk_bf16(p2, p3);
            af.u[2] = pk_bf16(p4, p5);
            af.u[3] = pk_bf16(p6, p7);

            acc2 = __builtin_amdgcn_mfma_f32_32x32x16_bf16(af.v, ONES.v, acc2, 0, 0, 0);
            acc0 = __builtin_amdgcn_mfma_f32_32x32x16_bf16(af.v, b0,     acc0, 0, 0, 0);
            acc1 = __builtin_amdgcn_mfma_f32_32x32x16_bf16(af.v, b1,     acc1, 0, 0, 0);
        }
    }

    __syncthreads();   // frag/tbl reads done -> overlay comb; psum2 region free

    // publish row sums (acc2 cols are identical; lanes l31==0 of each half write)
    if (l31 == 0) {
        #pragma unroll
        for (int reg = 0; reg < 16; ++reg) {
            const int r = (reg & 3) + 8*(reg >> 2) + 4*half;
            psum2[jh*64 + rg*32 + r] = acc2[reg];
        }
    }
    if (jh == 1) {     // odd waves (ks 2,3) publish partial accumulators
        float* cb = comb + (rg*64 + lane)*34;
        #pragma unroll
        for (int i = 0; i < 8; ++i) {
            float2 v0; v0.x = acc0[2*i]; v0.y = acc0[2*i+1];
            float2 v1; v1.x = acc1[2*i]; v1.y = acc1[2*i+1];
            *(float2*)&cb[2*i]      = v0;
            *(float2*)&cb[16 + 2*i] = v1;
        }
    }
    __syncthreads();
    if (jh == 0) {     // even waves merge + normalize + store
        const float* cb = comb + (rg*64 + lane)*34;
        #pragma unroll
        for (int i = 0; i < 8; ++i) {
            const float2 v0 = *(const float2*)&cb[2*i];
            const float2 v1 = *(const float2*)&cb[16 + 2*i];
            acc0[2*i] += v0.x; acc0[2*i+1] += v0.y;
            acc1[2*i] += v1.x; acc1[2*i+1] += v1.y;
        }
        #pragma unroll
        for (int reg = 0; reg < 16; ++reg) {
            const int r = (reg & 3) + 8*(reg >> 2) + 4*half;
            const int row = rg*32 + r;
            const float inv = __builtin_amdgcn_rcpf(psum2[row] + psum2[64 + row]);
            const size_t base = ((size_t)g*NN + i0 + row)*NF;
            out[base + l31]      = acc0[reg] * inv;
            out[base + l31 + 32] = acc1[reg] * inv;
        }
    }
}

// ---------------------------------------------------------------------------
extern "C" void kernel_launch(void* const* d_in, const int* in_sizes, int n_in,
                              void* d_out, int out_size, void* d_ws, size_t ws_size,
                              hipStream_t stream)
{
    const float* h     = (const float*)d_in[0];
    const float* adj   = (const float*)d_in[1];
    const float* w     = (const float*)d_in[2];
    const float* a_src = (const float*)d_in[3];
    const float* a_dst = (const float*)d_in[4];
    float* out = (float*)d_out;

    char* ws = (char*)d_ws;
    // ws: hpt bf16 [64][16][4096] frag-order (8,388,608) | asrc (262,144)
    //     | edP (262,144) | edN (262,144) | bits u64 [4][1024][16] (524,288)
    unsigned short* hpt = (unsigned short*)ws;
    float* asrc         = (float*)(ws + 8388608);
    float* edP          = (float*)(ws + 8388608 + 262144);
    float* edN          = (float*)(ws + 8388608 + 524288);
    unsigned long long* bits = (unsigned long long*)(ws + 8388608 + 786432);

    gA_produce<<<dim3(1024), dim3(256), 0, stream>>>(
        h, adj, w, a_src, a_dst, hpt, asrc, edP, edN, bits);
    gC_attn<<<dim3(1024), dim3(256), 0, stream>>>(
        hpt, asrc, edP, edN, bits, out);
}

// Round 10
// 118.575 us; speedup vs baseline: 1.2058x; 1.1255x over previous
//
#include <hip/hip_runtime.h>
#include <hip/hip_bf16.h>
#include <math.h>

// Problem constants
#define NB 4
#define NC 4
#define NH 4
#define NN 1024
#define NF 64
#define NCOMBO 64
#define LEAK 0.2f

typedef __attribute__((ext_vector_type(8)))  short  short8;
typedef __attribute__((ext_vector_type(16))) float  float16;

// packed RNE f32x2 -> bf16x2 via v_cvt_pk_bf16_f32 (.x -> low 16, .y -> high 16)
static __device__ __forceinline__ unsigned pk_bf16(float a, float b) {
    union { __hip_bfloat162 h; unsigned u; } cv;
    cv.h = __float22bfloat162_rn(make_float2(a, b));
    return cv.u;
}

// tanh via hardware exp+rcp: 1 - 2/(1+e^{2x}); err ~1e-6, saturates correctly
static __device__ __forceinline__ float fast_tanh(float x) {
    const float e = __expf(2.f * x);
    return 1.f - 2.f * __builtin_amdgcn_rcpf(1.f + e);
}

// async global->LDS, 16B per lane (dst = wave-uniform base + lane*16)
static __device__ __forceinline__ void async_cp16(const void* gsrc, void* ldst) {
    __builtin_amdgcn_global_load_lds(
        (const __attribute__((address_space(1))) unsigned int*)gsrc,
        (__attribute__((address_space(3))) unsigned int*)ldst, 16, 0, 0);
}

// split 8 fp32 -> hi/lo bf16 short8 pair (x = hi + lo, both RNE bf16)
static __device__ __forceinline__ void split8(const float4 a, const float4 b,
                                              short8* hi, short8* lo) {
    union { short8 v; unsigned u[4]; } H, L;
    const float x[8] = {a.x,a.y,a.z,a.w,b.x,b.y,b.z,b.w};
    float lov[8];
    #pragma unroll
    for (int p = 0; p < 4; ++p) {
        const unsigned pk = pk_bf16(x[2*p], x[2*p+1]);
        H.u[p] = pk;
        union { unsigned u; float f; } f0, f1;
        f0.u = pk << 16; f1.u = pk & 0xffff0000u;
        lov[2*p]   = x[2*p]   - f0.f;
        lov[2*p+1] = x[2*p+1] - f1.f;
    }
    #pragma unroll
    for (int p = 0; p < 4; ++p) L.u[p] = pk_bf16(lov[2*p], lov[2*p+1]);
    *hi = H.v; *lo = L.v;
}

// ---------------------------------------------------------------------------
// gA: producer, MFMA version. Block idx -> (g, tile), XCD-aligned swizzle
// (idx%8 == g>>3 in both kernels). 64 n-rows per block, 4 waves:
// wave = (rg = wv>>1 row group of 32, oh = wv&1 o-half of 32).
//   hp = h@w via split-bf16 MFMA (Ahi*Bhi + Alo*Bhi + Ahi*Blo, fp32 acc
//   -> hp accurate to ~1e-4). tanh+scores from acc via butterfly reduce.
//   hp written direct from C-layout regs to frag-order hpt (coalesced 8B).
//   Also writes asrc, edP=exp(dst), edN=exp(0.2 dst), and adj bitmask.
// ---------------------------------------------------------------------------
__global__ __launch_bounds__(256) void gA_produce(
    const float* __restrict__ h, const float* __restrict__ adj,
    const float* __restrict__ w, const float* __restrict__ a_src,
    const float* __restrict__ a_dst,
    unsigned short* __restrict__ hpt, float* __restrict__ asrc,
    float* __restrict__ edPt, float* __restrict__ edNt,
    unsigned long long* __restrict__ bits)
{
    // [0,16384): w_s fp32 [64][64]  ->  overlay whi [0,8192) + wlo [8192,16384)
    // [16384,16640): as_lds | [16640,16896): ad_lds
    // [16896,17408): scS[64][2] | [17408,17920): scD[64][2]
    __shared__ __align__(16) char smem[17920];
    float* w_s    = (float*)smem;
    unsigned short* whi = (unsigned short*)smem;          // 4096 bf16
    unsigned short* wlo = (unsigned short*)(smem + 8192); // 4096 bf16
    float* as_lds = (float*)(smem + 16384);
    float* ad_lds = (float*)(smem + 16640);
    float* scS    = (float*)(smem + 16896);
    float* scD    = (float*)(smem + 17408);

    const int idx  = blockIdx.x;
    const int t    = threadIdx.x;
    const int g    = (idx & 7)*8 + ((idx >> 3) & 7);   // 0..63
    const int tile = idx >> 6;                          // 0..15
    const int b = g >> 4, c = (g >> 2) & 3, hh = g & 3;
    const int lane = t & 63, l31 = lane & 31, half = lane >> 5;
    const int wv = t >> 6, rg = wv >> 1, oh = wv & 1;

    // ---- stage w fp32 + score vectors ----
    const float4* wsrc = (const float4*)(w + ((size_t)(c*NH + hh))*NF*NF);
    #pragma unroll
    for (int i = 0; i < 4; ++i)
        ((float4*)w_s)[t + i*256] = wsrc[t + i*256];
    if (t < NF) {
        as_lds[t] = a_src[(c*NH + hh)*NF + t];
        ad_lds[t] = a_dst[(c*NH + hh)*NF + t];
    }
    __syncthreads();

    // ---- read w values for B-frag packing into regs (before overlay) ----
    // thread handles blk = t>>5 and blk+8; blk = (ks*2+sub)*2+hf, n = t&31
    float wv0[8], wv1[8];
    {
        const int n = t & 31;
        #pragma unroll
        for (int j = 0; j < 8; ++j) {
            const int blk0 = t >> 5, blk1 = (t >> 5) + 8;
            const int k0 = (blk0 >> 2)*16 + (blk0 & 1)*8 + j;
            const int o0 = ((blk0 >> 1) & 1)*32 + n;
            const int k1 = (blk1 >> 2)*16 + (blk1 & 1)*8 + j;
            const int o1 = ((blk1 >> 1) & 1)*32 + n;
            wv0[j] = w_s[k0*64 + o0];
            wv1[j] = w_s[k1*64 + o1];
        }
    }
    // ---- A-fragments: rows tile*64 + rg*32 + l31, k = s*16 + half*8 + j ----
    short8 ahi[4], alo[4];
    {
        const float* hrow = h +
            (((size_t)(b*NC + c))*NN + tile*64 + rg*32 + l31)*NF;
        #pragma unroll
        for (int s = 0; s < 4; ++s) {
            const float4 v0 = *(const float4*)&hrow[s*16 + half*8];
            const float4 v1 = *(const float4*)&hrow[s*16 + half*8 + 4];
            split8(v0, v1, &ahi[s], &alo[s]);
        }
    }
    __syncthreads();   // w_s reads done -> overlay frags

    // ---- write w B-frags (hi/lo) ----
    {
        union { short8 v; unsigned u[4]; } H; short8 L;
        float4 a0 = make_float4(wv0[0],wv0[1],wv0[2],wv0[3]);
        float4 a1 = make_float4(wv0[4],wv0[5],wv0[6],wv0[7]);
        split8(a0, a1, &H.v, &L);
        *(short8*)&whi[((t >> 5)*32 + (t & 31))*8] = H.v;
        *(short8*)&wlo[((t >> 5)*32 + (t & 31))*8] = L;
        a0 = make_float4(wv1[0],wv1[1],wv1[2],wv1[3]);
        a1 = make_float4(wv1[4],wv1[5],wv1[6],wv1[7]);
        split8(a0, a1, &H.v, &L);
        *(short8*)&whi[(((t >> 5) + 8)*32 + (t & 31))*8] = H.v;
        *(short8*)&wlo[(((t >> 5) + 8)*32 + (t & 31))*8] = L;
    }
    __syncthreads();

    // ---- MFMA: acc(32 rows x 32 o) = sum_s A[s] * B[s][oh] ----
    float16 acc;
    #pragma unroll
    for (int i = 0; i < 16; ++i) acc[i] = 0.f;
    #pragma unroll
    for (int s = 0; s < 4; ++s) {
        const short8 bhi = *(const short8*)&whi[(((s*2 + oh)*2 + half)*32 + l31)*8];
        const short8 blo = *(const short8*)&wlo[(((s*2 + oh)*2 + half)*32 + l31)*8];
        acc = __builtin_amdgcn_mfma_f32_32x32x16_bf16(ahi[s], bhi, acc, 0, 0, 0);
        acc = __builtin_amdgcn_mfma_f32_32x32x16_bf16(alo[s], bhi, acc, 0, 0, 0);
        acc = __builtin_amdgcn_mfma_f32_32x32x16_bf16(ahi[s], blo, acc, 0, 0, 0);
    }

    // ---- scores: s[row] = sum_o tanh(hp)*a[o]; butterfly over 32 cols ----
    {
        const int col = oh*32 + l31;
        const float av = as_lds[col], dv = ad_lds[col];
        float sS[16], sD[16];
        #pragma unroll
        for (int reg = 0; reg < 16; ++reg) {
            const float tt = fast_tanh(acc[reg]);
            sS[reg] = tt * av;
            sD[reg] = tt * dv;
        }
        #pragma unroll
        for (int off = 1; off <= 16; off <<= 1) {
            #pragma unroll
            for (int reg = 0; reg < 16; ++reg) {
                sS[reg] += __shfl_xor(sS[reg], off);
                sD[reg] += __shfl_xor(sD[reg], off);
            }
        }
        if (l31 == 0) {
            #pragma unroll
            for (int reg = 0; reg < 16; ++reg) {
                const int row = rg*32 + (reg & 3) + 8*(reg >> 2) + 4*half;
                scS[row*2 + oh] = sS[reg];
                scD[row*2 + oh] = sD[reg];
            }
        }
    }

    // ---- hp -> hpt (bf16, frag order), coalesced 8B stores ----
    {
        unsigned short* dst = hpt + ((size_t)(g*16 + tile))*4096;
        #pragma unroll
        for (int q = 0; q < 4; ++q) {
            const int ks = rg*2 + (q >> 1), hf = q & 1;
            const int elem = (((ks*2 + oh)*2 + hf)*32 + l31)*8 + 4*half;
            uint2 pk;
            pk.x = pk_bf16(acc[q*4 + 0], acc[q*4 + 1]);
            pk.y = pk_bf16(acc[q*4 + 2], acc[q*4 + 3]);
            *(uint2*)&dst[elem] = pk;
        }
    }
    __syncthreads();
    if (t < 64) {
        const float s = scS[t*2] + scS[t*2 + 1];
        const float d = scD[t*2] + scD[t*2 + 1];
        asrc[(size_t)g*NN + tile*64 + t] = s;
        edPt[(size_t)g*NN + tile*64 + t] = __expf(d);
        edNt[(size_t)g*NN + tile*64 + t] = __expf(LEAK*d);
    }

    // ---- phase B: adjacency bitmask (this block's 4096-element chunk) ----
    {
        const int base = idx*4096;       // 1024 blocks x 4096 = 4M elements
        #pragma unroll
        for (int q = 0; q < 16; ++q) {
            const int e  = base + q*256 + t;
            const int j  = e & (NN-1);
            const int i  = (e >> 10) & (NN-1);
            const int bb = e >> 20;
            const bool pred = (adj[e] != 0.f) || (j == i);
            const unsigned long long m = __ballot(pred);
            if ((t & 63) == 0) bits[((size_t)bb*NN + i)*16 + (j >> 6)] = m;
        }
    }
}

// ---------------------------------------------------------------------------
// gC: consumer (UNCHANGED from R8). Double-buffered async-DMA frag staging,
// packed bf16 exp tables in LDS, row-sum via ones-MFMA.
// p_raw = mask * max(edP_j, ratio_i*edN_j), ratio_i = exp((LEAK-1)*sv_i).
// ---------------------------------------------------------------------------
__global__ __launch_bounds__(256, 4) void gC_attn(
    const unsigned short* __restrict__ hpt, const float* __restrict__ asrc,
    const float* __restrict__ edPt, const float* __restrict__ edNt,
    const unsigned long long* __restrict__ bits, float* __restrict__ out)
{
    __shared__ __align__(16) char smem[29696];
    unsigned short* fragB = (unsigned short*)smem;
    unsigned*       tbl   = (unsigned*)(smem + 16384);
    float*          comb  = (float*)smem;
    unsigned long long* bits_lds = (unsigned long long*)(smem + 20480);
    float*          psum2 = (float*)(smem + 29184);

    const int idx = blockIdx.x;
    const int t   = threadIdx.x;
    const int g   = (idx & 7)*8 + ((idx >> 3) & 7);
    const int it  = idx >> 6;
    const int b   = g >> 4;
    const int i0  = it*64;
    const int wv = t >> 6, lane = t & 63;
    const int l31 = lane & 31, half = lane >> 5;
    const int rg = wv >> 1, jh = wv & 1;
    const int myrow = rg*32 + l31;

    {
        const char* gs = (const char*)hpt + ((size_t)g*16)*8192 + wv*2048 + lane*16;
        char* ls = smem + wv*2048;
        async_cp16(gs, ls);
        async_cp16(gs + 1024, ls + 1024);
    }
    #pragma unroll
    for (int q = 0; q < 4; ++q) {
        const int j = q*256 + t;
        tbl[j] = pk_bf16(edNt[(size_t)g*NN + j], edPt[(size_t)g*NN + j]);
    }
    {
        const unsigned long long* bsrc = bits + ((size_t)b*NN + i0)*16;
        #pragma unroll
        for (int q = 0; q < 4; ++q) {
            const int e = q*256 + t;
            bits_lds[(e >> 4)*17 + (e & 15)] = bsrc[e];
        }
    }
    const float sv    = asrc[(size_t)g*NN + i0 + myrow];
    const float ratio = __expf((LEAK - 1.f)*sv);

    union { short8 v; unsigned short u[8]; } ONES;
    #pragma unroll
    for (int i = 0; i < 8; ++i) ONES.u[i] = 0x3F80;

    float16 acc0, acc1, acc2;
    #pragma unroll
    for (int i = 0; i < 16; ++i) { acc0[i] = 0.f; acc1[i] = 0.f; acc2[i] = 0.f; }

    for (int jt = 0; jt < 16; ++jt) {
        __syncthreads();
        const int fb = jt & 1;
        if (jt < 15) {
            const char* gs = (const char*)hpt + ((size_t)g*16 + jt + 1)*8192
                             + wv*2048 + lane*16;
            char* ls = smem + ((jt + 1) & 1)*8192 + wv*2048;
            async_cp16(gs, ls);
            async_cp16(gs + 1024, ls + 1024);
        }
        const unsigned long long wb = bits_lds[myrow*17 + jt];

        #pragma unroll
        for (int kk = 0; kk < 2; ++kk) {
            const int ks = jh*2 + kk;
            const int jo = ks*16 + half*8;
            const uint4 Ta = *(const uint4*)&tbl[jt*64 + jo];
            const uint4 Tb = *(const uint4*)&tbl[jt*64 + jo + 4];
            const short8 b0 = *(const short8*)
                &fragB[fb*4096 + (((ks*2 + 0)*2 + half)*32 + l31)*8];
            const short8 b1 = *(const short8*)
                &fragB[fb*4096 + (((ks*2 + 1)*2 + half)*32 + l31)*8];
            const unsigned bb = (unsigned)(wb >> jo) & 0xffu;

            float p0, p1, p2, p3, p4, p5, p6, p7;
            {
                union { unsigned u; float f; } hi, lo;
                hi.u = Ta.x & 0xffff0000u; lo.u = Ta.x << 16;
                p0 = fmaxf(hi.f, ratio*lo.f); p0 = (bb & 1u)   ? p0 : 0.f;
                hi.u = Ta.y & 0xffff0000u; lo.u = Ta.y << 16;
                p1 = fmaxf(hi.f, ratio*lo.f); p1 = (bb & 2u)   ? p1 : 0.f;
                hi.u = Ta.z & 0xffff0000u; lo.u = Ta.z << 16;
                p2 = fmaxf(hi.f, ratio*lo.f); p2 = (bb & 4u)   ? p2 : 0.f;
                hi.u = Ta.w & 0xffff0000u; lo.u = Ta.w << 16;
                p3 = fmaxf(hi.f, ratio*lo.f); p3 = (bb & 8u)   ? p3 : 0.f;
                hi.u = Tb.x & 0xffff0000u; lo.u = Tb.x << 16;
                p4 = fmaxf(hi.f, ratio*lo.f); p4 = (bb & 16u)  ? p4 : 0.f;
                hi.u = Tb.y & 0xffff0000u; lo.u = Tb.y << 16;
                p5 = fmaxf(hi.f, ratio*lo.f); p5 = (bb & 32u)  ? p5 : 0.f;
                hi.u = Tb.z & 0xffff0000u; lo.u = Tb.z << 16;
                p6 = fmaxf(hi.f, ratio*lo.f); p6 = (bb & 64u)  ? p6 : 0.f;
                hi.u = Tb.w & 0xffff0000u; lo.u = Tb.w << 16;
                p7 = fmaxf(hi.f, ratio*lo.f); p7 = (bb & 128u) ? p7 : 0.f;
            }

            union { short8 v; unsigned u[4]; } af;
            af.u[0] = pk_bf16(p0, p1);
            af.u[1] = pk_bf16(p2, p3);
            af.u[2] = pk_bf16(p4, p5);
            af.u[3] = pk_bf16(p6, p7);

            acc2 = __builtin_amdgcn_mfma_f32_32x32x16_bf16(af.v, ONES.v, acc2, 0, 0, 0);
            acc0 = __builtin_amdgcn_mfma_f32_32x32x16_bf16(af.v, b0,     acc0, 0, 0, 0);
            acc1 = __builtin_amdgcn_mfma_f32_32x32x16_bf16(af.v, b1,     acc1, 0, 0, 0);
        }
    }

    __syncthreads();

    if (l31 == 0) {
        #pragma unroll
        for (int reg = 0; reg < 16; ++reg) {
            const int r = (reg & 3) + 8*(reg >> 2) + 4*half;
            psum2[jh*64 + rg*32 + r] = acc2[reg];
        }
    }
    if (jh == 1) {
        float* cb = comb + (rg*64 + lane)*34;
        #pragma unroll
        for (int i = 0; i < 8; ++i) {
            float2 v0; v0.x = acc0[2*i]; v0.y = acc0[2*i+1];
            float2 v1; v1.x = acc1[2*i]; v1.y = acc1[2*i+1];
            *(float2*)&cb[2*i]      = v0;
            *(float2*)&cb[16 + 2*i] = v1;
        }
    }
    __syncthreads();
    if (jh == 0) {
        const float* cb = comb + (rg*64 + lane)*34;
        #pragma unroll
        for (int i = 0; i < 8; ++i) {
            const float2 v0 = *(const float2*)&cb[2*i];
            const float2 v1 = *(const float2*)&cb[16 + 2*i];
            acc0[2*i] += v0.x; acc0[2*i+1] += v0.y;
            acc1[2*i] += v1.x; acc1[2*i+1] += v1.y;
        }
        #pragma unroll
        for (int reg = 0; reg < 16; ++reg) {
            const int r = (reg & 3) + 8*(reg >> 2) + 4*half;
            const int row = rg*32 + r;
            const float inv = __builtin_amdgcn_rcpf(psum2[row] + psum2[64 + row]);
            const size_t base = ((size_t)g*NN + i0 + row)*NF;
            out[base + l31]      = acc0[reg] * inv;
            out[base + l31 + 32] = acc1[reg] * inv;
        }
    }
}

// ---------------------------------------------------------------------------
extern "C" void kernel_launch(void* const* d_in, const int* in_sizes, int n_in,
                              void* d_out, int out_size, void* d_ws, size_t ws_size,
                              hipStream_t stream)
{
    const float* h     = (const float*)d_in[0];
    const float* adj   = (const float*)d_in[1];
    const float* w     = (const float*)d_in[2];
    const float* a_src = (const float*)d_in[3];
    const float* a_dst = (const float*)d_in[4];
    float* out = (float*)d_out;

    char* ws = (char*)d_ws;
    // ws: hpt bf16 [64][16][4096] frag-order (8,388,608) | asrc (262,144)
    //     | edP (262,144) | edN (262,144) | bits u64 [4][1024][16] (524,288)
    unsigned short* hpt = (unsigned short*)ws;
    float* asrc         = (float*)(ws + 8388608);
    float* edP          = (float*)(ws + 8388608 + 262144);
    float* edN          = (float*)(ws + 8388608 + 524288);
    unsigned long long* bits = (unsigned long long*)(ws + 8388608 + 786432);

    gA_produce<<<dim3(1024), dim3(256), 0, stream>>>(
        h, adj, w, a_src, a_dst, hpt, asrc, edP, edN, bits);
    gC_attn<<<dim3(1024), dim3(256), 0, stream>>>(
        hpt, asrc, edP, edN, bits, out);
}